// Round 7
// baseline (749.918 us; speedup 1.0000x reference)
//
#include <hip/hip_runtime.h>

#define NN 100000
#define NE 3200000
#define NB 391        // coarse buckets: dst>>8, 256 nodes each
#define CAP 9216      // per-bucket pair capacity (mean 8184, sigma~90, +11 sigma)
#define PB 16         // edges per thread in bin_kernel
#define CH_A (256 * PB)

typedef _Float16 half4 __attribute__((ext_vector_type(4)));
typedef _Float16 half8 __attribute__((ext_vector_type(8)));

// ---------- helpers ----------
__device__ __forceinline__ float4 f4fma(float s, float4 a, float4 c) {
  c.x = fmaf(s, a.x, c.x); c.y = fmaf(s, a.y, c.y);
  c.z = fmaf(s, a.z, c.z); c.w = fmaf(s, a.w, c.w);
  return c;
}

template<int CTRL>
__device__ __forceinline__ float4 quad_bcast(float4 v) {
  float4 r;
  r.x = __int_as_float(__builtin_amdgcn_update_dpp(__float_as_int(v.x), __float_as_int(v.x), CTRL, 0xF, 0xF, false));
  r.y = __int_as_float(__builtin_amdgcn_update_dpp(__float_as_int(v.y), __float_as_int(v.y), CTRL, 0xF, 0xF, false));
  r.z = __int_as_float(__builtin_amdgcn_update_dpp(__float_as_int(v.z), __float_as_int(v.z), CTRL, 0xF, 0xF, false));
  r.w = __int_as_float(__builtin_amdgcn_update_dpp(__float_as_int(v.w), __float_as_int(v.w), CTRL, 0xF, 0xF, false));
  return r;
}

// edge_index may be int32 or int64 (values < 2^31, nonneg -> int64 high words 0)
__device__ __forceinline__ int edge_val(const int* __restrict__ ei, int idx, bool w64) {
  return w64 ? ei[2 * idx] : ei[idx];
}

// ---------- kernels ----------
// zero bucket_cursor + detect int64 layout (1 block)
__global__ __launch_bounds__(512) void init_kernel(const int* __restrict__ ei,
                                                   int* __restrict__ bucket_cursor,
                                                   int* __restrict__ flag) {
  int t = threadIdx.x;
  if (t < NB) bucket_cursor[t] = 0;
  if (t == 511) {
    int o = 0;
    for (int i = 1; i < 64; i += 2) o |= ei[i];
    *flag = (o == 0) ? 1 : 0;   // 1 => int64 layout
  }
}

// Pass A: coarse-bucket edges, coalesced PACKED writes (src|24b + dstlow<<24).
__global__ __launch_bounds__(256) void bin_kernel(const int* __restrict__ ei,
                                                  int* __restrict__ bucket_cursor,
                                                  int* __restrict__ pairs,
                                                  const int* __restrict__ flag) {
  __shared__ int  cnt[4][NB];
  __shared__ int  wcur[4][NB];   // per-wave staging cursor (block-local slot)
  __shared__ int  lbase[NB];     // block-local exclusive scan of bucket totals
  __shared__ int  gbase[NB];     // reserved base within bucket region
  __shared__ int  sc[512];
  __shared__ int2 stage[CH_A];   // 32 KB
  int t = threadIdx.x;
  int wv = t >> 6;
  for (int k = t; k < 4 * NB; k += 256) (&cnt[0][0])[k] = 0;
  __syncthreads();
  bool w64 = (*flag != 0);
  int base = blockIdx.x * CH_A;
  int nval = min(CH_A, NE - base);
  int s[PB], d[PB];
#pragma unroll
  for (int i = 0; i < PB; ++i) {
    int e = base + i * 256 + t;
    if (e < NE) {
      s[i] = edge_val(ei, e, w64);
      d[i] = edge_val(ei, NE + e, w64);
      atomicAdd(&cnt[wv][d[i] >> 8], 1);
    } else {
      d[i] = -1;
    }
  }
  __syncthreads();
  // block scan over bucket totals (512-wide, 2 per thread)
  int tA = (t < NB) ? cnt[0][t] + cnt[1][t] + cnt[2][t] + cnt[3][t] : 0;
  int tB = (t + 256 < NB) ? cnt[0][t + 256] + cnt[1][t + 256] + cnt[2][t + 256] + cnt[3][t + 256] : 0;
  sc[t] = tA; sc[t + 256] = tB;
  __syncthreads();
#pragma unroll
  for (int off = 1; off < 512; off <<= 1) {
    int u0 = (t >= off) ? sc[t - off] : 0;
    int u1 = (t + 256 >= off) ? sc[t + 256 - off] : 0;
    __syncthreads();
    sc[t] += u0; sc[t + 256] += u1;
    __syncthreads();
  }
#pragma unroll
  for (int h = 0; h < 2; ++h) {
    int k = t + h * 256;
    if (k < NB) {
      int tot = (h == 0) ? tA : tB;
      int lb = sc[k] - tot;
      lbase[k] = lb;
      gbase[k] = (tot > 0) ? atomicAdd(&bucket_cursor[k], tot) : 0;
      int c0 = cnt[0][k], c1 = cnt[1][k], c2 = cnt[2][k];
      wcur[0][k] = lb;
      wcur[1][k] = lb + c0;
      wcur[2][k] = lb + c0 + c1;
      wcur[3][k] = lb + c0 + c1 + c2;
    }
  }
  __syncthreads();
#pragma unroll
  for (int i = 0; i < PB; ++i) {
    if (d[i] >= 0) {
      int b = d[i] >> 8;
      int slot = atomicAdd(&wcur[wv][b], 1);
      stage[slot] = make_int2(s[i], d[i]);
    }
  }
  __syncthreads();
  // coalesced writeout: consecutive k are runs within one bucket; packed 4B
  for (int k = t; k < nval; k += 256) {
    int2 p = stage[k];
    int b = p.y >> 8;
    pairs[(size_t)b * CAP + gbase[b] + (k - lbase[b])] = p.x | ((p.y & 255) << 24);
  }
}

// per-bucket degree histogram -> dinv (no CSR needed)
__global__ __launch_bounds__(256) void degscan_kernel(const int* __restrict__ pairs,
                                                      const int* __restrict__ bucket_cursor,
                                                      float* __restrict__ dinv) {
  __shared__ int hist[256];
  int t = threadIdx.x;
  int b = blockIdx.x;
  int cnt_b = bucket_cursor[b];
  size_t in_base = (size_t)b * CAP;
  hist[t] = 0;
  __syncthreads();
  for (int i = t; i < cnt_b; i += 256)
    atomicAdd(&hist[((unsigned)pairs[in_base + i]) >> 24], 1);
  __syncthreads();
  int n = b * 256 + t;
  if (n < NN) dinv[n] = rsqrtf((float)hist[t] + 1.0f);  // +1 self loop
}

// xw1h[n][16] = fp16( dinv[n] * (x[n][256] @ W1[256][16]) ); wave = 8 nodes.
__global__ __launch_bounds__(256) void gemm1_kernel(const float* __restrict__ x,
                                                    const float* __restrict__ W1,
                                                    const float* __restrict__ dinv,
                                                    _Float16* __restrict__ xw1h) {
  const int lane = threadIdx.x & 63;
  const int wv   = threadIdx.x >> 6;
  const int node0 = (blockIdx.x * 4 + wv) * 8;
  const int cg = lane >> 2;
  const int jl = lane & 3;
  float4 w[16];
#pragma unroll
  for (int k = 0; k < 4; ++k)
#pragma unroll
    for (int c = 0; c < 4; ++c)
      w[k * 4 + c] = *(const float4*)(W1 + (cg * 16 + k * 4 + c) * 16 + jl * 4);
  float4 xv[8];
#pragma unroll
  for (int i = 0; i < 8; ++i)
    xv[i] = *(const float4*)(x + (size_t)(node0 + i) * 256 + lane * 4);
  float4 acc[8];
#pragma unroll
  for (int i = 0; i < 8; ++i) acc[i] = make_float4(0.f, 0.f, 0.f, 0.f);
#pragma unroll
  for (int i = 0; i < 8; ++i) {
    float4 b = quad_bcast<0x00>(xv[i]);
    acc[i] = f4fma(b.x, w[0], acc[i]);  acc[i] = f4fma(b.y, w[1], acc[i]);
    acc[i] = f4fma(b.z, w[2], acc[i]);  acc[i] = f4fma(b.w, w[3], acc[i]);
  }
#pragma unroll
  for (int i = 0; i < 8; ++i) {
    float4 b = quad_bcast<0x55>(xv[i]);
    acc[i] = f4fma(b.x, w[4], acc[i]);  acc[i] = f4fma(b.y, w[5], acc[i]);
    acc[i] = f4fma(b.z, w[6], acc[i]);  acc[i] = f4fma(b.w, w[7], acc[i]);
  }
#pragma unroll
  for (int i = 0; i < 8; ++i) {
    float4 b = quad_bcast<0xAA>(xv[i]);
    acc[i] = f4fma(b.x, w[8], acc[i]);  acc[i] = f4fma(b.y, w[9], acc[i]);
    acc[i] = f4fma(b.z, w[10], acc[i]); acc[i] = f4fma(b.w, w[11], acc[i]);
  }
#pragma unroll
  for (int i = 0; i < 8; ++i) {
    float4 b = quad_bcast<0xFF>(xv[i]);
    acc[i] = f4fma(b.x, w[12], acc[i]); acc[i] = f4fma(b.y, w[13], acc[i]);
    acc[i] = f4fma(b.z, w[14], acc[i]); acc[i] = f4fma(b.w, w[15], acc[i]);
  }
#pragma unroll
  for (int m = 4; m <= 32; m <<= 1) {
#pragma unroll
    for (int i = 0; i < 8; ++i) {
      acc[i].x += __shfl_xor(acc[i].x, m);
      acc[i].y += __shfl_xor(acc[i].y, m);
      acc[i].z += __shfl_xor(acc[i].z, m);
      acc[i].w += __shfl_xor(acc[i].w, m);
    }
  }
  if (lane < 4) {
#pragma unroll
    for (int i = 0; i < 8; ++i) {
      float dn = dinv[node0 + i];
      float4 a = acc[i];
      half4 hv;
      hv[0] = (_Float16)(a.x * dn); hv[1] = (_Float16)(a.y * dn);
      hv[2] = (_Float16)(a.z * dn); hv[3] = (_Float16)(a.w * dn);
      *(half4*)(xw1h + (size_t)(node0 + i) * 16 + lane * 4) = hv;
    }
  }
}

// Layer 1, edge-major per bucket: LDS-accumulate gather(xw1h), then per-node
// self-loop + bias + relu + @W2, store fp16 pre-scaled by dinv[n].
#define A1S 17   // padded row stride (floats) to break bank alignment
__global__ __launch_bounds__(512) void layer1_kernel(const int* __restrict__ pairs,
                                                     const int* __restrict__ bucket_cursor,
                                                     const float* __restrict__ dinv,
                                                     const _Float16* __restrict__ xw1h,
                                                     const float* __restrict__ W2,
                                                     const float* __restrict__ b1,
                                                     _Float16* __restrict__ h1w2h) {
  __shared__ float agg[256 * A1S];
  int t = threadIdx.x;
  int b = blockIdx.x;
  int cnt_b = bucket_cursor[b];
  size_t in_base = (size_t)b * CAP;
  for (int k = t; k < 256 * A1S; k += 512) agg[k] = 0.f;
  __syncthreads();
  int q = t & 3;
  for (int i = t >> 2; i < cnt_b; i += 128) {
    int pk = pairs[in_base + i];
    int s = pk & 0xFFFFFF;
    int dl = ((unsigned)pk) >> 24;
    half4 v = *(const half4*)(xw1h + (size_t)s * 16 + q * 4);
    float* ap = agg + dl * A1S + q * 4;
    atomicAdd(ap + 0, (float)v[0]);
    atomicAdd(ap + 1, (float)v[1]);
    atomicAdd(ap + 2, (float)v[2]);
    atomicAdd(ap + 3, (float)v[3]);
  }
  __syncthreads();
  // epilogue: 2 threads per node, each handles 8 of 16 h-features
  int nl = t >> 1, hh = t & 1;
  int n = b * 256 + nl;
  if (n >= NN) return;
  float dn = dinv[n];
  half8 svh = *(const half8*)(xw1h + (size_t)n * 16 + hh * 8);
  float p[8] = {0.f, 0.f, 0.f, 0.f, 0.f, 0.f, 0.f, 0.f};
#pragma unroll
  for (int f8 = 0; f8 < 8; ++f8) {
    int f = hh * 8 + f8;
    float hv = fmaxf(fmaf(dn, agg[nl * A1S + f] + (float)svh[f8], b1[f]), 0.f);
    const float4* W2v = (const float4*)(W2 + f * 8);
    float4 wlo = W2v[0], whi = W2v[1];
    p[0] = fmaf(hv, wlo.x, p[0]); p[1] = fmaf(hv, wlo.y, p[1]);
    p[2] = fmaf(hv, wlo.z, p[2]); p[3] = fmaf(hv, wlo.w, p[3]);
    p[4] = fmaf(hv, whi.x, p[4]); p[5] = fmaf(hv, whi.y, p[5]);
    p[6] = fmaf(hv, whi.z, p[6]); p[7] = fmaf(hv, whi.w, p[7]);
  }
#pragma unroll
  for (int j = 0; j < 8; ++j) p[j] += __shfl_xor(p[j], 1);
  if (hh == 0) {
    half8 hv;
#pragma unroll
    for (int j = 0; j < 8; ++j) hv[j] = (_Float16)(p[j] * dn);
    *(half8*)(h1w2h + (size_t)n * 8) = hv;
  }
}

// Layer 2, edge-major per bucket: LDS-accumulate gather(h1w2h), then per-node
// self-loop + bias + log_softmax(8) -> out.
#define A2S 9
__global__ __launch_bounds__(512) void layer2_kernel(const int* __restrict__ pairs,
                                                     const int* __restrict__ bucket_cursor,
                                                     const float* __restrict__ dinv,
                                                     const _Float16* __restrict__ h1w2h,
                                                     const float* __restrict__ b2,
                                                     float* __restrict__ out) {
  __shared__ float agg[256 * A2S];
  int t = threadIdx.x;
  int b = blockIdx.x;
  int cnt_b = bucket_cursor[b];
  size_t in_base = (size_t)b * CAP;
  for (int k = t; k < 256 * A2S; k += 512) agg[k] = 0.f;
  __syncthreads();
  int q = t & 1;
  for (int i = t >> 1; i < cnt_b; i += 256) {
    int pk = pairs[in_base + i];
    int s = pk & 0xFFFFFF;
    int dl = ((unsigned)pk) >> 24;
    half4 v = *(const half4*)(h1w2h + (size_t)s * 8 + q * 4);
    float* ap = agg + dl * A2S + q * 4;
    atomicAdd(ap + 0, (float)v[0]);
    atomicAdd(ap + 1, (float)v[1]);
    atomicAdd(ap + 2, (float)v[2]);
    atomicAdd(ap + 3, (float)v[3]);
  }
  __syncthreads();
  if (t >= 256) return;
  int n = b * 256 + t;
  if (n >= NN) return;
  float dn = dinv[n];
  half8 svh = *(const half8*)(h1w2h + (size_t)n * 8);
  float v[8];
#pragma unroll
  for (int j = 0; j < 8; ++j)
    v[j] = fmaf(dn, agg[t * A2S + j] + (float)svh[j], b2[j]);
  float m = v[0];
#pragma unroll
  for (int j = 1; j < 8; ++j) m = fmaxf(m, v[j]);
  float sum = 0.f;
#pragma unroll
  for (int j = 0; j < 8; ++j) sum += expf(v[j] - m);
  float ls = m + logf(sum);
  *(float4*)(out + (size_t)n * 8)     = make_float4(v[0] - ls, v[1] - ls, v[2] - ls, v[3] - ls);
  *(float4*)(out + (size_t)n * 8 + 4) = make_float4(v[4] - ls, v[5] - ls, v[6] - ls, v[7] - ls);
}

// ---------- launch ----------
extern "C" void kernel_launch(void* const* d_in, const int* in_sizes, int n_in,
                              void* d_out, int out_size, void* d_ws, size_t ws_size,
                              hipStream_t stream) {
  const float* x  = (const float*)d_in[0];
  const int*   ei = (const int*)d_in[1];
  const float* W1 = (const float*)d_in[2];
  const float* b1 = (const float*)d_in[3];
  const float* W2 = (const float*)d_in[4];
  const float* b2 = (const float*)d_in[5];
  float* out = (float*)d_out;

  // workspace (no aliasing: pairs stays live through layer2)
  int*      pairs = (int*)d_ws;                                   // NB*CAP ints (14.4MB)
  _Float16* xw1h  = (_Float16*)(pairs + (size_t)NB * CAP);        // 16N halves (3.2MB)
  _Float16* h1w2h = xw1h + (size_t)16 * NN;                       // 8N halves (1.6MB)
  float*    dinv  = (float*)(h1w2h + (size_t)8 * NN);             // N floats
  int*      bucket_cursor = (int*)(dinv + NN);                    // NB
  int*      flag  = bucket_cursor + NB;                           // 1

  init_kernel<<<1, 512, 0, stream>>>(ei, bucket_cursor, flag);
  bin_kernel<<<(NE + CH_A - 1) / CH_A, 256, 0, stream>>>(ei, bucket_cursor, pairs, flag);
  degscan_kernel<<<NB, 256, 0, stream>>>(pairs, bucket_cursor, dinv);
  gemm1_kernel<<<NN / 32, 256, 0, stream>>>(x, W1, dinv, xw1h);
  layer1_kernel<<<NB, 512, 0, stream>>>(pairs, bucket_cursor, dinv, xw1h, W2, b1, h1w2h);
  layer2_kernel<<<NB, 512, 0, stream>>>(pairs, bucket_cursor, dinv, h1w2h, b2, out);
}

// Round 8
// 321.080 us; speedup vs baseline: 2.3356x; 2.3356x over previous
//
#include <hip/hip_runtime.h>

#define NN 100000
#define NE 3200000
#define NB 391        // coarse buckets: dst>>8, 256 nodes each
#define CAP 9216      // per-bucket pair capacity (mean 8184, sigma~90, +11 sigma)
#define PB 16         // edges per thread in bin_kernel
#define CH_A (256 * PB)

typedef _Float16 half4 __attribute__((ext_vector_type(4)));
typedef _Float16 half8 __attribute__((ext_vector_type(8)));

// ---------- helpers ----------
__device__ __forceinline__ float4 f4fma(float s, float4 a, float4 c) {
  c.x = fmaf(s, a.x, c.x); c.y = fmaf(s, a.y, c.y);
  c.z = fmaf(s, a.z, c.z); c.w = fmaf(s, a.w, c.w);
  return c;
}

template<int CTRL>
__device__ __forceinline__ float4 quad_bcast(float4 v) {
  float4 r;
  r.x = __int_as_float(__builtin_amdgcn_update_dpp(__float_as_int(v.x), __float_as_int(v.x), CTRL, 0xF, 0xF, false));
  r.y = __int_as_float(__builtin_amdgcn_update_dpp(__float_as_int(v.y), __float_as_int(v.y), CTRL, 0xF, 0xF, false));
  r.z = __int_as_float(__builtin_amdgcn_update_dpp(__float_as_int(v.z), __float_as_int(v.z), CTRL, 0xF, 0xF, false));
  r.w = __int_as_float(__builtin_amdgcn_update_dpp(__float_as_int(v.w), __float_as_int(v.w), CTRL, 0xF, 0xF, false));
  return r;
}

// edge_index may be int32 or int64 (values < 2^31, nonneg -> int64 high words 0)
__device__ __forceinline__ int edge_val(const int* __restrict__ ei, int idx, bool w64) {
  return w64 ? ei[2 * idx] : ei[idx];
}

// ---------- kernels ----------
// zero bucket_cursor + detect int64 layout (1 block)
__global__ __launch_bounds__(512) void init_kernel(const int* __restrict__ ei,
                                                   int* __restrict__ bucket_cursor,
                                                   int* __restrict__ flag) {
  int t = threadIdx.x;
  if (t < NB) bucket_cursor[t] = 0;
  if (t == 511) {
    int o = 0;
    for (int i = 1; i < 64; i += 2) o |= ei[i];
    *flag = (o == 0) ? 1 : 0;   // 1 => int64 layout
  }
}

// Pass A: coarse-bucket edges, coalesced PACKED writes (src|24b + dstlow<<24).
__global__ __launch_bounds__(256) void bin_kernel(const int* __restrict__ ei,
                                                  int* __restrict__ bucket_cursor,
                                                  int* __restrict__ pairs,
                                                  const int* __restrict__ flag) {
  __shared__ int  cnt[4][NB];
  __shared__ int  wcur[4][NB];   // per-wave staging cursor (block-local slot)
  __shared__ int  lbase[NB];     // block-local exclusive scan of bucket totals
  __shared__ int  gbase[NB];     // reserved base within bucket region
  __shared__ int  sc[512];
  __shared__ int2 stage[CH_A];   // 32 KB
  int t = threadIdx.x;
  int wv = t >> 6;
  for (int k = t; k < 4 * NB; k += 256) (&cnt[0][0])[k] = 0;
  __syncthreads();
  bool w64 = (*flag != 0);
  int base = blockIdx.x * CH_A;
  int nval = min(CH_A, NE - base);
  int s[PB], d[PB];
#pragma unroll
  for (int i = 0; i < PB; ++i) {
    int e = base + i * 256 + t;
    if (e < NE) {
      s[i] = edge_val(ei, e, w64);
      d[i] = edge_val(ei, NE + e, w64);
      atomicAdd(&cnt[wv][d[i] >> 8], 1);
    } else {
      d[i] = -1;
    }
  }
  __syncthreads();
  // block scan over bucket totals (512-wide, 2 per thread)
  int tA = (t < NB) ? cnt[0][t] + cnt[1][t] + cnt[2][t] + cnt[3][t] : 0;
  int tB = (t + 256 < NB) ? cnt[0][t + 256] + cnt[1][t + 256] + cnt[2][t + 256] + cnt[3][t + 256] : 0;
  sc[t] = tA; sc[t + 256] = tB;
  __syncthreads();
#pragma unroll
  for (int off = 1; off < 512; off <<= 1) {
    int u0 = (t >= off) ? sc[t - off] : 0;
    int u1 = (t + 256 >= off) ? sc[t + 256 - off] : 0;
    __syncthreads();
    sc[t] += u0; sc[t + 256] += u1;
    __syncthreads();
  }
#pragma unroll
  for (int h = 0; h < 2; ++h) {
    int k = t + h * 256;
    if (k < NB) {
      int tot = (h == 0) ? tA : tB;
      int lb = sc[k] - tot;
      lbase[k] = lb;
      gbase[k] = (tot > 0) ? atomicAdd(&bucket_cursor[k], tot) : 0;
      int c0 = cnt[0][k], c1 = cnt[1][k], c2 = cnt[2][k];
      wcur[0][k] = lb;
      wcur[1][k] = lb + c0;
      wcur[2][k] = lb + c0 + c1;
      wcur[3][k] = lb + c0 + c1 + c2;
    }
  }
  __syncthreads();
#pragma unroll
  for (int i = 0; i < PB; ++i) {
    if (d[i] >= 0) {
      int b = d[i] >> 8;
      int slot = atomicAdd(&wcur[wv][b], 1);
      stage[slot] = make_int2(s[i], d[i]);
    }
  }
  __syncthreads();
  // coalesced writeout: consecutive k are runs within one bucket; packed 4B
  for (int k = t; k < nval; k += 256) {
    int2 p = stage[k];
    int b = p.y >> 8;
    pairs[(size_t)b * CAP + gbase[b] + (k - lbase[b])] = p.x | ((p.y & 255) << 24);
  }
}

// exclusive scan of NB (<=512) bucket counts, single block of 256
__global__ __launch_bounds__(256) void bscan_kernel(const int* __restrict__ bucket_cursor,
                                                    int* __restrict__ bucket_scan) {
  __shared__ int sc[512];
  __shared__ int orig[512];
  int t = threadIdx.x;
  int v0 = (t < NB) ? bucket_cursor[t] : 0;
  int v1 = (t + 256 < NB) ? bucket_cursor[t + 256] : 0;
  sc[t] = v0; orig[t] = v0;
  sc[t + 256] = v1; orig[t + 256] = v1;
  __syncthreads();
#pragma unroll
  for (int off = 1; off < 512; off <<= 1) {
    int u0 = (t >= off) ? sc[t - off] : 0;
    int u1 = (t + 256 >= off) ? sc[t + 256 - off] : 0;
    __syncthreads();
    sc[t] += u0; sc[t + 256] += u1;
    __syncthreads();
  }
  if (t < NB) bucket_scan[t] = sc[t] - orig[t];
  if (t + 256 < NB) bucket_scan[t + 256] = sc[t + 256] - orig[t + 256];
}

// Pass B: one 512-thread block per 256-node bucket. Per-node histogram, scan
// -> deg/row_ofs/dinv, scatter src into srt within a ~32KB window.
__global__ __launch_bounds__(512) void sort_kernel(const int* __restrict__ pairs,
                                                   const int* __restrict__ bucket_cursor,
                                                   const int* __restrict__ bucket_scan,
                                                   int* __restrict__ srt,
                                                   int* __restrict__ deg,
                                                   int* __restrict__ row_ofs,
                                                   float* __restrict__ dinv) {
  __shared__ int hist[256];
  __shared__ int sc[256];
  __shared__ int cur[256];
  int t = threadIdx.x;
  int b = blockIdx.x;
  int cnt_b = bucket_cursor[b];
  size_t in_base = (size_t)b * CAP;
  int out_base = bucket_scan[b];
  if (t < 256) hist[t] = 0;
  __syncthreads();
  for (int i = t; i < cnt_b; i += 512) {
    int pk = pairs[in_base + i];
    atomicAdd(&hist[((unsigned)pk) >> 24], 1);
  }
  __syncthreads();
  if (t < 256) sc[t] = hist[t];
  __syncthreads();
#pragma unroll
  for (int off = 1; off < 256; off <<= 1) {
    int u = (t < 256 && t >= off) ? sc[t - off] : 0;
    __syncthreads();
    if (t < 256) sc[t] += u;
    __syncthreads();
  }
  if (t < 256) {
    int excl = sc[t] - hist[t];
    cur[t] = out_base + excl;
    int n = b * 256 + t;
    if (n < NN) {
      deg[n] = hist[t];
      row_ofs[n] = out_base + excl;
      dinv[n] = rsqrtf((float)hist[t] + 1.0f);  // +1 self loop
    }
  }
  __syncthreads();
  for (int i = t; i < cnt_b; i += 512) {
    int pk = pairs[in_base + i];
    int pos = atomicAdd(&cur[((unsigned)pk) >> 24], 1);
    srt[pos] = pk & 0xFFFFFF;
  }
}

// xw1h[n][16] = fp16( dinv[n] * (x[n][256] @ W1[256][16]) ); wave = 8 nodes.
__global__ __launch_bounds__(256) void gemm1_kernel(const float* __restrict__ x,
                                                    const float* __restrict__ W1,
                                                    const float* __restrict__ dinv,
                                                    _Float16* __restrict__ xw1h) {
  const int lane = threadIdx.x & 63;
  const int wv   = threadIdx.x >> 6;
  const int node0 = (blockIdx.x * 4 + wv) * 8;
  const int cg = lane >> 2;
  const int jl = lane & 3;
  float4 w[16];
#pragma unroll
  for (int k = 0; k < 4; ++k)
#pragma unroll
    for (int c = 0; c < 4; ++c)
      w[k * 4 + c] = *(const float4*)(W1 + (cg * 16 + k * 4 + c) * 16 + jl * 4);
  float4 xv[8];
#pragma unroll
  for (int i = 0; i < 8; ++i)
    xv[i] = *(const float4*)(x + (size_t)(node0 + i) * 256 + lane * 4);
  float4 acc[8];
#pragma unroll
  for (int i = 0; i < 8; ++i) acc[i] = make_float4(0.f, 0.f, 0.f, 0.f);
#pragma unroll
  for (int i = 0; i < 8; ++i) {
    float4 b = quad_bcast<0x00>(xv[i]);
    acc[i] = f4fma(b.x, w[0], acc[i]);  acc[i] = f4fma(b.y, w[1], acc[i]);
    acc[i] = f4fma(b.z, w[2], acc[i]);  acc[i] = f4fma(b.w, w[3], acc[i]);
  }
#pragma unroll
  for (int i = 0; i < 8; ++i) {
    float4 b = quad_bcast<0x55>(xv[i]);
    acc[i] = f4fma(b.x, w[4], acc[i]);  acc[i] = f4fma(b.y, w[5], acc[i]);
    acc[i] = f4fma(b.z, w[6], acc[i]);  acc[i] = f4fma(b.w, w[7], acc[i]);
  }
#pragma unroll
  for (int i = 0; i < 8; ++i) {
    float4 b = quad_bcast<0xAA>(xv[i]);
    acc[i] = f4fma(b.x, w[8], acc[i]);  acc[i] = f4fma(b.y, w[9], acc[i]);
    acc[i] = f4fma(b.z, w[10], acc[i]); acc[i] = f4fma(b.w, w[11], acc[i]);
  }
#pragma unroll
  for (int i = 0; i < 8; ++i) {
    float4 b = quad_bcast<0xFF>(xv[i]);
    acc[i] = f4fma(b.x, w[12], acc[i]); acc[i] = f4fma(b.y, w[13], acc[i]);
    acc[i] = f4fma(b.z, w[14], acc[i]); acc[i] = f4fma(b.w, w[15], acc[i]);
  }
#pragma unroll
  for (int m = 4; m <= 32; m <<= 1) {
#pragma unroll
    for (int i = 0; i < 8; ++i) {
      acc[i].x += __shfl_xor(acc[i].x, m);
      acc[i].y += __shfl_xor(acc[i].y, m);
      acc[i].z += __shfl_xor(acc[i].z, m);
      acc[i].w += __shfl_xor(acc[i].w, m);
    }
  }
  if (lane < 4) {
#pragma unroll
    for (int i = 0; i < 8; ++i) {
      float dn = dinv[node0 + i];
      float4 a = acc[i];
      half4 hv;
      hv[0] = (_Float16)(a.x * dn); hv[1] = (_Float16)(a.y * dn);
      hv[2] = (_Float16)(a.z * dn); hv[3] = (_Float16)(a.w * dn);
      *(half4*)(xw1h + (size_t)(node0 + i) * 16 + lane * 4) = hv;
    }
  }
}

// Layer 1 fused: gather(xw1h) + self-loop + bias + relu + @W2, fp16 out.
// 16 lanes per node: q = feat group (4 feats), e = edge quarter (stride 4).
__global__ __launch_bounds__(256) void layer1_kernel(const int* __restrict__ srt,
                                                     const int* __restrict__ row_ofs,
                                                     const int* __restrict__ deg,
                                                     const float* __restrict__ dinv,
                                                     const _Float16* __restrict__ xw1h,
                                                     const float* __restrict__ W2,
                                                     const float* __restrict__ b1,
                                                     _Float16* __restrict__ h1w2h) {
  int t = blockIdx.x * 256 + threadIdx.x;
  int n = t >> 4, sub = t & 15, q = sub & 3, e = sub >> 2;
  if (n >= NN) return;
  int base = row_ofs[n], cnt = deg[n];
  float4 acc = make_float4(0.f, 0.f, 0.f, 0.f);
  int s_next = (e < cnt) ? srt[base + e] : 0;
  for (int i = e; i < cnt; i += 4) {
    int s = s_next;
    if (i + 4 < cnt) s_next = srt[base + i + 4];
    half4 v = *(const half4*)(xw1h + (size_t)s * 16 + q * 4);
    acc.x += (float)v[0]; acc.y += (float)v[1];
    acc.z += (float)v[2]; acc.w += (float)v[3];
  }
  // combine edge quarters (lane bits 2,3) -> all lanes hold full sum
#pragma unroll
  for (int m = 4; m <= 8; m <<= 1) {
    acc.x += __shfl_xor(acc.x, m);
    acc.y += __shfl_xor(acc.y, m);
    acc.z += __shfl_xor(acc.z, m);
    acc.w += __shfl_xor(acc.w, m);
  }
  float dn = dinv[n];
  half4 svh = *(const half4*)(xw1h + (size_t)n * 16 + q * 4);
  float4 bv = *(const float4*)(b1 + q * 4);
  float h[4];
  h[0] = fmaxf(fmaf(dn, acc.x + (float)svh[0], bv.x), 0.f);
  h[1] = fmaxf(fmaf(dn, acc.y + (float)svh[1], bv.y), 0.f);
  h[2] = fmaxf(fmaf(dn, acc.z + (float)svh[2], bv.z), 0.f);
  h[3] = fmaxf(fmaf(dn, acc.w + (float)svh[3], bv.w), 0.f);
  float p[8] = {0.f, 0.f, 0.f, 0.f, 0.f, 0.f, 0.f, 0.f};
  const float4* W2v = (const float4*)W2;
#pragma unroll
  for (int f = 0; f < 4; ++f) {
    float4 wlo = W2v[(q * 4 + f) * 2];
    float4 whi = W2v[(q * 4 + f) * 2 + 1];
    p[0] = fmaf(h[f], wlo.x, p[0]); p[1] = fmaf(h[f], wlo.y, p[1]);
    p[2] = fmaf(h[f], wlo.z, p[2]); p[3] = fmaf(h[f], wlo.w, p[3]);
    p[4] = fmaf(h[f], whi.x, p[4]); p[5] = fmaf(h[f], whi.y, p[5]);
    p[6] = fmaf(h[f], whi.z, p[6]); p[7] = fmaf(h[f], whi.w, p[7]);
  }
  // reduce over q (lane bits 0,1) -> all lanes hold full p[0..7]
#pragma unroll
  for (int m = 1; m <= 2; m <<= 1)
#pragma unroll
    for (int j = 0; j < 8; ++j)
      p[j] += __shfl_xor(p[j], m);
  if (sub == 0) {
    half8 hv;
#pragma unroll
    for (int j = 0; j < 8; ++j) hv[j] = (_Float16)(p[j] * dn);
    *(half8*)(h1w2h + (size_t)n * 8) = hv;
  }
}

// Layer 2 fused: gather(h1w2h) + self-loop + bias + log_softmax(8).
// 8 lanes per node: q = feat half (4 feats), e = edge quarter (stride 4).
__global__ __launch_bounds__(256) void layer2_kernel(const int* __restrict__ srt,
                                                     const int* __restrict__ row_ofs,
                                                     const int* __restrict__ deg,
                                                     const float* __restrict__ dinv,
                                                     const _Float16* __restrict__ h1w2h,
                                                     const float* __restrict__ b2,
                                                     float* __restrict__ out) {
  int t = blockIdx.x * 256 + threadIdx.x;
  int n = t >> 3, sub = t & 7, q = sub & 1, e = sub >> 1;
  if (n >= NN) return;
  int base = row_ofs[n], cnt = deg[n];
  float4 acc = make_float4(0.f, 0.f, 0.f, 0.f);
  int s_next = (e < cnt) ? srt[base + e] : 0;
  for (int i = e; i < cnt; i += 4) {
    int s = s_next;
    if (i + 4 < cnt) s_next = srt[base + i + 4];
    half4 v = *(const half4*)(h1w2h + (size_t)s * 8 + q * 4);
    acc.x += (float)v[0]; acc.y += (float)v[1];
    acc.z += (float)v[2]; acc.w += (float)v[3];
  }
  // combine edge quarters (lane bits 1,2) -> all lanes hold full feat-half sum
#pragma unroll
  for (int m = 2; m <= 4; m <<= 1) {
    acc.x += __shfl_xor(acc.x, m);
    acc.y += __shfl_xor(acc.y, m);
    acc.z += __shfl_xor(acc.z, m);
    acc.w += __shfl_xor(acc.w, m);
  }
  float dn = dinv[n];
  half4 svh = *(const half4*)(h1w2h + (size_t)n * 8 + q * 4);
  float4 bv = *(const float4*)(b2 + q * 4);
  float4 v;
  v.x = fmaf(dn, acc.x + (float)svh[0], bv.x);
  v.y = fmaf(dn, acc.y + (float)svh[1], bv.y);
  v.z = fmaf(dn, acc.z + (float)svh[2], bv.z);
  v.w = fmaf(dn, acc.w + (float)svh[3], bv.w);
  float mh = fmaxf(fmaxf(v.x, v.y), fmaxf(v.z, v.w));
  float m = fmaxf(mh, __shfl_xor(mh, 1));
  float se = expf(v.x - m) + expf(v.y - m) + expf(v.z - m) + expf(v.w - m);
  float st = se + __shfl_xor(se, 1);
  float ls = m + logf(st);
  if (sub < 2)
    *(float4*)(out + (size_t)n * 8 + q * 4) = make_float4(v.x - ls, v.y - ls, v.z - ls, v.w - ls);
}

// ---------- launch ----------
extern "C" void kernel_launch(void* const* d_in, const int* in_sizes, int n_in,
                              void* d_out, int out_size, void* d_ws, size_t ws_size,
                              hipStream_t stream) {
  const float* x  = (const float*)d_in[0];
  const int*   ei = (const int*)d_in[1];
  const float* W1 = (const float*)d_in[2];
  const float* b1 = (const float*)d_in[3];
  const float* W2 = (const float*)d_in[4];
  const float* b2 = (const float*)d_in[5];
  float* out = (float*)d_out;

  // workspace (no aliasing; ~33 MB total)
  int*      pairs = (int*)d_ws;                                   // NB*CAP ints (14.4MB)
  _Float16* xw1h  = (_Float16*)(pairs + (size_t)NB * CAP);        // 16N halves (3.2MB)
  _Float16* h1w2h = xw1h + (size_t)16 * NN;                       // 8N halves (1.6MB)
  float*    dinv  = (float*)(h1w2h + (size_t)8 * NN);             // N floats
  int*      deg   = (int*)(dinv + NN);                            // N
  int*      row_ofs = deg + NN;                                   // N
  int*      srt   = row_ofs + NN;                                 // NE (12.8MB)
  int*      bucket_cursor = srt + NE;                             // NB
  int*      bucket_scan   = bucket_cursor + NB + 1;               // NB
  int*      flag          = bucket_scan + NB + 1;                 // 1

  init_kernel<<<1, 512, 0, stream>>>(ei, bucket_cursor, flag);
  bin_kernel<<<(NE + CH_A - 1) / CH_A, 256, 0, stream>>>(ei, bucket_cursor, pairs, flag);
  bscan_kernel<<<1, 256, 0, stream>>>(bucket_cursor, bucket_scan);
  sort_kernel<<<NB, 512, 0, stream>>>(pairs, bucket_cursor, bucket_scan, srt, deg, row_ofs, dinv);
  gemm1_kernel<<<NN / 32, 256, 0, stream>>>(x, W1, dinv, xw1h);
  layer1_kernel<<<(16 * NN + 255) / 256, 256, 0, stream>>>(srt, row_ofs, deg, dinv, xw1h, W2, b1, h1w2h);
  layer2_kernel<<<(8 * NN + 255) / 256, 256, 0, stream>>>(srt, row_ofs, deg, dinv, h1w2h, b2, out);
}